// Round 1
// baseline (306.160 us; speedup 1.0000x reference)
//
#include <hip/hip_runtime.h>
#include <math.h>

#define EPSF 1e-5f

// ---------------------------------------------------------------------------
// k1: per-(b,c) plane -> row/col means -> strip pool (x + conv3 + conv7)/3 -> BN
// writes sp[b][c][0..127]  (l<64: h-strip, l>=64: w-strip)
// ---------------------------------------------------------------------------
__global__ __launch_bounds__(256) void k1_pool_strip(
    const float* __restrict__ x,
    const float* __restrict__ sph_w3, const float* __restrict__ sph_w7,
    const float* __restrict__ sph_g,  const float* __restrict__ sph_b,
    const float* __restrict__ sph_m,  const float* __restrict__ sph_v,
    const float* __restrict__ spw_w3, const float* __restrict__ spw_w7,
    const float* __restrict__ spw_g,  const float* __restrict__ spw_b,
    const float* __restrict__ spw_m,  const float* __restrict__ spw_v,
    float* __restrict__ sp)
{
    __shared__ __align__(16) float tile[64][68];   // stride 68: 16B-aligned rows, +4 bank skew
    __shared__ float mh[64];   // row means  (mean over w) -> x_h
    __shared__ float mw[64];   // col means  (mean over h) -> x_w

    const int plane = blockIdx.x;          // b*256 + c
    const int c = plane & 255;
    const float* xp = x + (size_t)plane * 4096;
    const int t = threadIdx.x;
    const int r = t >> 2, q = t & 3;

    // coalesced: each thread loads 16 consecutive floats of row r
    const float4* src = (const float4*)(xp + r * 64 + q * 16);
    float4* dst = (float4*)&tile[r][q * 16];
    dst[0] = src[0]; dst[1] = src[1]; dst[2] = src[2]; dst[3] = src[3];
    __syncthreads();

    if (t < 64) {
        // column sum -> x_w mean
        float s = 0.f;
        for (int rr = 0; rr < 64; ++rr) s += tile[rr][t];
        mw[t] = s * (1.f / 64.f);
    } else if (t < 128) {
        // row sum -> x_h mean (stagger start col to avoid bank conflicts)
        const int rr = t - 64;
        float s = 0.f;
        for (int i = 0; i < 64; ++i) s += tile[rr][(rr + i) & 63];
        mh[rr] = s * (1.f / 64.f);
    }
    __syncthreads();

    if (t < 128) {
        const int l = t & 63;
        const bool is_h = (t < 64);
        const float* m  = is_h ? mh     : mw;
        const float* w3 = is_h ? sph_w3 : spw_w3;
        const float* w7 = is_h ? sph_w7 : spw_w7;
        const float* g  = is_h ? sph_g  : spw_g;
        const float* bb = is_h ? sph_b  : spw_b;
        const float* mu = is_h ? sph_m  : spw_m;
        const float* vv = is_h ? sph_v  : spw_v;

        float v[7];
        #pragma unroll
        for (int j = 0; j < 7; ++j) {
            int idx = l - 3 + j;
            v[j] = (idx >= 0 && idx < 64) ? m[idx] : 0.f;
        }
        // cross-correlation (jax conv_general_dilated does not flip kernels)
        float c3 = w3[c*3+0]*v[2] + w3[c*3+1]*v[3] + w3[c*3+2]*v[4];
        float c7 = 0.f;
        #pragma unroll
        for (int j = 0; j < 7; ++j) c7 += w7[c*7+j]*v[j];

        float o = (v[3] + c3 + c7) * (1.f / 3.f);
        float scale = g[c] * rsqrtf(vv[c] + EPSF);
        o = (o - mu[c]) * scale + bb[c];
        sp[(size_t)plane * 128 + (is_h ? l : 64 + l)] = o;
    }
}

// ---------------------------------------------------------------------------
// k2: per-batch: y = bn1(hswish input)(conv1_w @ sp), then
//     a_h = sigmoid(convh_w @ y_h), a_w = sigmoid(convw_w @ y_w)
// ---------------------------------------------------------------------------
__global__ __launch_bounds__(256) void k2_mid(
    const float* __restrict__ sp,
    const float* __restrict__ conv1_w,
    const float* __restrict__ bn1_g, const float* __restrict__ bn1_b,
    const float* __restrict__ bn1_m, const float* __restrict__ bn1_v,
    const float* __restrict__ convh_w, const float* __restrict__ convw_w,
    float* __restrict__ a_h, float* __restrict__ a_w)
{
    __shared__ float w1[2048];     // conv1_w  (8 x 256)
    __shared__ float wh[2048];     // convh_w  (256 x 8)
    __shared__ float ww[2048];     // convw_w  (256 x 8)
    __shared__ float y[8][128];
    __shared__ float bnp[4][8];

    const int b = blockIdx.x;
    const int t = threadIdx.x;

    for (int i = t; i < 2048; i += 256) {
        w1[i] = conv1_w[i];
        wh[i] = convh_w[i];
        ww[i] = convw_w[i];
    }
    if (t < 8) {
        bnp[0][t] = bn1_g[t]; bnp[1][t] = bn1_b[t];
        bnp[2][t] = bn1_m[t]; bnp[3][t] = bn1_v[t];
    }
    __syncthreads();

    // thread t handles (m = mb+2j, l);  m is wave-uniform -> LDS broadcast
    const int l = t & 127, mb = t >> 7;
    const float* spb = sp + (size_t)b * 256 * 128;
    float acc[4] = {0.f, 0.f, 0.f, 0.f};
    for (int cc = 0; cc < 256; ++cc) {
        float vv = spb[cc * 128 + l];          // coalesced
        acc[0] += w1[(mb + 0) * 256 + cc] * vv;
        acc[1] += w1[(mb + 2) * 256 + cc] * vv;
        acc[2] += w1[(mb + 4) * 256 + cc] * vv;
        acc[3] += w1[(mb + 6) * 256 + cc] * vv;
    }
    #pragma unroll
    for (int j = 0; j < 4; ++j) {
        int m = mb + 2 * j;
        float val = acc[j];
        float scale = bnp[0][m] * rsqrtf(bnp[3][m] + EPSF);
        val = (val - bnp[2][m]) * scale + bnp[1][m];
        val = val * fminf(fmaxf(val + 3.f, 0.f), 6.f) * (1.f / 6.f);  // hswish
        y[m][l] = val;
    }
    __syncthreads();

    float* ahb = a_h + (size_t)b * 256 * 64;
    float* awb = a_w + (size_t)b * 256 * 64;
    for (int i = 0; i < 64; ++i) {
        int idx = i * 256 + t;
        int o = idx >> 6, h = idx & 63;        // o wave-uniform, h coalesced
        float sh = 0.f, sw = 0.f;
        #pragma unroll
        for (int m = 0; m < 8; ++m) {
            sh += wh[o * 8 + m] * y[m][h];
            sw += ww[o * 8 + m] * y[m][64 + h];
        }
        ahb[idx] = 1.f / (1.f + __expf(-sh));
        awb[idx] = 1.f / (1.f + __expf(-sw));
    }
}

// ---------------------------------------------------------------------------
// k3: out[b,c,h,w] = x[b,c,h,w] * a_h[b,c,h] * a_w[b,c,w]   (float4)
// ---------------------------------------------------------------------------
__global__ __launch_bounds__(256) void k3_apply(
    const float* __restrict__ x,
    const float* __restrict__ a_h, const float* __restrict__ a_w,
    float* __restrict__ out)
{
    const size_t g = (size_t)blockIdx.x * 256 + threadIdx.x;
    float4 xv = ((const float4*)x)[g];
    const size_t idx = g * 4;
    const int w0 = (int)(idx & 63);
    const int h  = (int)((idx >> 6) & 63);
    const size_t bc = idx >> 12;
    const float ah = a_h[bc * 64 + h];
    const float4 aw = *(const float4*)(a_w + bc * 64 + w0);
    float4 o;
    o.x = xv.x * ah * aw.x;
    o.y = xv.y * ah * aw.y;
    o.z = xv.z * ah * aw.z;
    o.w = xv.w * ah * aw.w;
    ((float4*)out)[g] = o;
}

// ---------------------------------------------------------------------------
extern "C" void kernel_launch(void* const* d_in, const int* in_sizes, int n_in,
                              void* d_out, int out_size, void* d_ws, size_t ws_size,
                              hipStream_t stream) {
    const float* x       = (const float*)d_in[0];
    const float* sph_w3  = (const float*)d_in[1];
    const float* sph_w7  = (const float*)d_in[2];
    const float* sph_g   = (const float*)d_in[3];
    const float* sph_b   = (const float*)d_in[4];
    const float* sph_m   = (const float*)d_in[5];
    const float* sph_v   = (const float*)d_in[6];
    const float* spw_w3  = (const float*)d_in[7];
    const float* spw_w7  = (const float*)d_in[8];
    const float* spw_g   = (const float*)d_in[9];
    const float* spw_b   = (const float*)d_in[10];
    const float* spw_m   = (const float*)d_in[11];
    const float* spw_v   = (const float*)d_in[12];
    const float* conv1_w = (const float*)d_in[13];
    const float* bn1_g   = (const float*)d_in[14];
    const float* bn1_b   = (const float*)d_in[15];
    const float* bn1_m   = (const float*)d_in[16];
    const float* bn1_v   = (const float*)d_in[17];
    const float* convh_w = (const float*)d_in[18];
    const float* convw_w = (const float*)d_in[19];

    float* ws  = (float*)d_ws;
    float* sp  = ws;                         // 32*256*128 = 1,048,576 floats
    float* a_h = ws + 1048576;               // 32*256*64  =   524,288
    float* a_w = ws + 1048576 + 524288;      // 32*256*64  =   524,288

    const int B = 32, C = 256;

    k1_pool_strip<<<B * C, 256, 0, stream>>>(
        x, sph_w3, sph_w7, sph_g, sph_b, sph_m, sph_v,
        spw_w3, spw_w7, spw_g, spw_b, spw_m, spw_v, sp);

    k2_mid<<<B, 256, 0, stream>>>(
        sp, conv1_w, bn1_g, bn1_b, bn1_m, bn1_v, convh_w, convw_w, a_h, a_w);

    // 32*256*64*64 / 4 floats-per-thread / 256 threads = 32768 blocks
    k3_apply<<<32768, 256, 0, stream>>>(x, a_h, a_w, (float*)d_out);
}

// Round 2
// 292.001 us; speedup vs baseline: 1.0485x; 1.0485x over previous
//
#include <hip/hip_runtime.h>
#include <math.h>

#define EPSF 1e-5f

// ---------------------------------------------------------------------------
// k1: per-(b,c) plane -> row/col means -> strip pool (x + conv3 + conv7)/3 -> BN
// writes sp[b][c][0..127]  (l<64: h-strip, l>=64: w-strip)
// Row sums folded into the load; col sums split across all 4 waves.
// ---------------------------------------------------------------------------
__global__ __launch_bounds__(256) void k1_pool_strip(
    const float* __restrict__ x,
    const float* __restrict__ sph_w3, const float* __restrict__ sph_w7,
    const float* __restrict__ sph_g,  const float* __restrict__ sph_b,
    const float* __restrict__ sph_m,  const float* __restrict__ sph_v,
    const float* __restrict__ spw_w3, const float* __restrict__ spw_w7,
    const float* __restrict__ spw_g,  const float* __restrict__ spw_b,
    const float* __restrict__ spw_m,  const float* __restrict__ spw_v,
    float* __restrict__ sp)
{
    __shared__ __align__(16) float tile[64][68];   // stride 68: 16B-aligned rows
    __shared__ __align__(16) float rpart[256];     // rpart[r*4+q] row partials
    __shared__ float cpart[4][64];                 // per-wave col partials
    __shared__ float mh[64];   // row means (mean over w) -> x_h
    __shared__ float mw[64];   // col means (mean over h) -> x_w

    const int plane = blockIdx.x;          // b*256 + c
    const int c = plane & 255;
    const float* xp = x + (size_t)plane * 4096;
    const int t = threadIdx.x;
    const int r = t >> 2, q = t & 3;

    // coalesced: thread t loads bytes [64t, 64t+64) = 16 floats of row r
    const float4* src = (const float4*)(xp + r * 64 + q * 16);
    float4 v0 = src[0], v1 = src[1], v2 = src[2], v3 = src[3];
    float4* dst = (float4*)&tile[r][q * 16];
    dst[0] = v0; dst[1] = v1; dst[2] = v2; dst[3] = v3;
    // row partial sum (16 floats) computed from registers — free
    rpart[t] = (v0.x + v0.y + v0.z + v0.w) + (v1.x + v1.y + v1.z + v1.w)
             + (v2.x + v2.y + v2.z + v2.w) + (v3.x + v3.y + v3.z + v3.w);
    __syncthreads();

    // col partials: wave qw sums rows [16qw, 16qw+16) of column cc
    {
        const int cc = t & 63, qw = t >> 6;
        float s = 0.f;
        #pragma unroll
        for (int i = 0; i < 16; ++i) s += tile[qw * 16 + i][cc];  // conflict-free
        cpart[qw][cc] = s;
    }
    __syncthreads();

    if (t < 64) {
        float4 rp = ((const float4*)rpart)[t];     // ds_read_b128, conflict-free
        mh[t] = (rp.x + rp.y + rp.z + rp.w) * (1.f / 64.f);
        mw[t] = (cpart[0][t] + cpart[1][t] + cpart[2][t] + cpart[3][t]) * (1.f / 64.f);
    }
    __syncthreads();

    if (t < 128) {
        const int l = t & 63;
        const bool is_h = (t < 64);
        const float* m  = is_h ? mh     : mw;
        const float* w3 = is_h ? sph_w3 : spw_w3;
        const float* w7 = is_h ? sph_w7 : spw_w7;
        const float* g  = is_h ? sph_g  : spw_g;
        const float* bb = is_h ? sph_b  : spw_b;
        const float* mu = is_h ? sph_m  : spw_m;
        const float* vv = is_h ? sph_v  : spw_v;

        float v[7];
        #pragma unroll
        for (int j = 0; j < 7; ++j) {
            int idx = l - 3 + j;
            v[j] = (idx >= 0 && idx < 64) ? m[idx] : 0.f;
        }
        // cross-correlation (jax conv_general_dilated does not flip kernels)
        float c3 = w3[c*3+0]*v[2] + w3[c*3+1]*v[3] + w3[c*3+2]*v[4];
        float c7 = 0.f;
        #pragma unroll
        for (int j = 0; j < 7; ++j) c7 += w7[c*7+j]*v[j];

        float o = (v[3] + c3 + c7) * (1.f / 3.f);
        float scale = g[c] * rsqrtf(vv[c] + EPSF);
        o = (o - mu[c]) * scale + bb[c];
        sp[(size_t)plane * 128 + (is_h ? l : 64 + l)] = o;
    }
}

// ---------------------------------------------------------------------------
// k2: grid = (32 batches x 8 l-chunks of 16).  Per block:
//   stage sp[b][:, l0:l0+16] (16 KB) in LDS, y = hswish(bn1(conv1_w @ sp)),
//   then a = sigmoid(conv{h,w}_w @ y) for 256 outputs x 16 positions.
// ---------------------------------------------------------------------------
__global__ __launch_bounds__(256) void k2_mid(
    const float* __restrict__ sp,
    const float* __restrict__ conv1_w,
    const float* __restrict__ bn1_g, const float* __restrict__ bn1_b,
    const float* __restrict__ bn1_m, const float* __restrict__ bn1_v,
    const float* __restrict__ convh_w, const float* __restrict__ convw_w,
    float* __restrict__ a_h, float* __restrict__ a_w)
{
    __shared__ float spc[256 * 16];   // spc[c][li]
    __shared__ float w1t[256 * 8];    // conv1_w transposed: w1t[c][m]
    __shared__ float wos[256 * 8];    // convh_w or convw_w (o-major), per-half
    __shared__ float ys[8 * 16];      // ys[m][li]

    const int b  = blockIdx.x >> 3;
    const int lc = blockIdx.x & 7;
    const int l0 = lc * 16;
    const bool is_h = (l0 < 64);
    const int t = threadIdx.x;

    const float* spb = sp + (size_t)b * 256 * 128;
    const float* wo  = is_h ? convh_w : convw_w;

    // stage: sp slab (coalesced 64B segments), weights
    for (int j = t; j < 4096; j += 256) {
        int cc = j >> 4, li = j & 15;
        spc[j] = spb[cc * 128 + l0 + li];
    }
    for (int j = t; j < 2048; j += 256) {
        int cc = j >> 3, m = j & 7;
        w1t[j] = conv1_w[m * 256 + cc];   // transpose (L2-hot, tiny)
        wos[j] = wo[j];
    }
    __syncthreads();

    // y[m][li] = hswish(bn1(sum_c w1[m][c] * sp[c][li]))
    if (t < 128) {
        const int m = t >> 4, li = t & 15;
        float acc = 0.f;
        for (int cc = 0; cc < 256; ++cc)
            acc += w1t[cc * 8 + m] * spc[cc * 16 + li];   // broadcast reads
        float scale = bn1_g[m] * rsqrtf(bn1_v[m] + EPSF);
        float val = (acc - bn1_m[m]) * scale + bn1_b[m];
        val = val * fminf(fmaxf(val + 3.f, 0.f), 6.f) * (1.f / 6.f);  // hswish
        ys[m * 16 + li] = val;
    }
    __syncthreads();

    // a[o][l0+li] = sigmoid(sum_m wo[o][m] * y[m][li])
    float* ab = (is_h ? a_h : a_w) + (size_t)b * 256 * 64;
    const int pos0 = is_h ? l0 : l0 - 64;
    const int li = t & 15, ob = t >> 4;
    #pragma unroll
    for (int i = 0; i < 16; ++i) {
        const int o = i * 16 + ob;
        float s = 0.f;
        #pragma unroll
        for (int m = 0; m < 8; ++m)
            s += wos[o * 8 + m] * ys[m * 16 + li];
        ab[o * 64 + pos0 + li] = 1.f / (1.f + __expf(-s));
    }
}

// ---------------------------------------------------------------------------
// k3: out[b,c,h,w] = x[b,c,h,w] * a_h[b,c,h] * a_w[b,c,w]   (float4)
// ---------------------------------------------------------------------------
__global__ __launch_bounds__(256) void k3_apply(
    const float* __restrict__ x,
    const float* __restrict__ a_h, const float* __restrict__ a_w,
    float* __restrict__ out)
{
    const size_t g = (size_t)blockIdx.x * 256 + threadIdx.x;
    float4 xv = ((const float4*)x)[g];
    const size_t idx = g * 4;
    const int w0 = (int)(idx & 63);
    const int h  = (int)((idx >> 6) & 63);
    const size_t bc = idx >> 12;
    const float ah = a_h[bc * 64 + h];
    const float4 aw = *(const float4*)(a_w + bc * 64 + w0);
    float4 o;
    o.x = xv.x * ah * aw.x;
    o.y = xv.y * ah * aw.y;
    o.z = xv.z * ah * aw.z;
    o.w = xv.w * ah * aw.w;
    ((float4*)out)[g] = o;
}

// ---------------------------------------------------------------------------
extern "C" void kernel_launch(void* const* d_in, const int* in_sizes, int n_in,
                              void* d_out, int out_size, void* d_ws, size_t ws_size,
                              hipStream_t stream) {
    const float* x       = (const float*)d_in[0];
    const float* sph_w3  = (const float*)d_in[1];
    const float* sph_w7  = (const float*)d_in[2];
    const float* sph_g   = (const float*)d_in[3];
    const float* sph_b   = (const float*)d_in[4];
    const float* sph_m   = (const float*)d_in[5];
    const float* sph_v   = (const float*)d_in[6];
    const float* spw_w3  = (const float*)d_in[7];
    const float* spw_w7  = (const float*)d_in[8];
    const float* spw_g   = (const float*)d_in[9];
    const float* spw_b   = (const float*)d_in[10];
    const float* spw_m   = (const float*)d_in[11];
    const float* spw_v   = (const float*)d_in[12];
    const float* conv1_w = (const float*)d_in[13];
    const float* bn1_g   = (const float*)d_in[14];
    const float* bn1_b   = (const float*)d_in[15];
    const float* bn1_m   = (const float*)d_in[16];
    const float* bn1_v   = (const float*)d_in[17];
    const float* convh_w = (const float*)d_in[18];
    const float* convw_w = (const float*)d_in[19];

    float* ws  = (float*)d_ws;
    float* sp  = ws;                         // 32*256*128 = 1,048,576 floats
    float* a_h = ws + 1048576;               // 32*256*64  =   524,288
    float* a_w = ws + 1048576 + 524288;      // 32*256*64  =   524,288

    const int B = 32, C = 256;

    k1_pool_strip<<<B * C, 256, 0, stream>>>(
        x, sph_w3, sph_w7, sph_g, sph_b, sph_m, sph_v,
        spw_w3, spw_w7, spw_g, spw_b, spw_m, spw_v, sp);

    k2_mid<<<B * 8, 256, 0, stream>>>(
        sp, conv1_w, bn1_g, bn1_b, bn1_m, bn1_v, convh_w, convw_w, a_h, a_w);

    // 32*256*64*64 / 4 floats-per-thread / 256 threads = 32768 blocks
    k3_apply<<<32768, 256, 0, stream>>>(x, a_h, a_w, (float*)d_out);
}